// Round 6
// baseline (201.015 us; speedup 1.0000x reference)
//
#include <hip/hip_runtime.h>
#include <math.h>

typedef _Float16 half8 __attribute__((ext_vector_type(8)));
typedef _Float16 half4 __attribute__((ext_vector_type(4)));
typedef float f32x4 __attribute__((ext_vector_type(4)));

#define HDIM 128
#define WHALFS 65536                      // packed W1|W2|W3 total halfs (128 KB)
#define SCR_HALFS 2048                    // per-wave scratch: 16 rows x 128 halfs (4 KB), XOR-swizzled
#define LDS_HALFS (WHALFS + 8 * SCR_HALFS)  // 81920 halfs
#define LDS_BYTES (LDS_HALFS * 2)           // 163840 B == 160 KiB exactly

// ---------------------------------------------------------------------------
// Prep: x (N x 128 fp32) -> fp16 (fully coalesced: 1 float4/lane, 16B stride
// on load, 8B stride on store); pack W1/W2/W3 into MFMA *A-operand* frag
// order for the transposed GEMM (A = W^T):
//   frag(ct,ks), lane: A[m=ct*16+(lane&15)][k=ks*32+(lane>>4)*8+j] = W[k][m]
// ---------------------------------------------------------------------------
__global__ __launch_bounds__(256) void prep_kernel(
    const float* __restrict__ x,  const float* __restrict__ W1,
    const float* __restrict__ W2, const float* __restrict__ W3,
    _Float16* __restrict__ xh,  _Float16* __restrict__ W1p,
    _Float16* __restrict__ W2p, _Float16* __restrict__ W3p, int NF)
{
    int bid = blockIdx.x;
    if (bid < 32) {
        int t = bid * 256 + threadIdx.x;   // 0..8191
        const float* W; _Float16* Wp; int KS; int u;
        if (t < 4096)      { W = W1; Wp = W1p; KS = 8; u = t; }          // 256x128
        else if (t < 6144) { W = W2; Wp = W2p; KS = 4; u = t - 4096; }   // 128x128
        else               { W = W3; Wp = W3p; KS = 4; u = t - 6144; }   // 128x128
        int lane = u & 63;
        int fk   = u >> 6;            // ct*KS + ks
        int ks   = fk % KS;
        int ct   = fk / KS;
        int m    = ct * 16 + (lane & 15);
        int k0   = ks * 32 + (lane >> 4) * 8;
        half8 v;
        #pragma unroll
        for (int j = 0; j < 8; ++j) v[j] = (_Float16)W[(k0 + j) * HDIM + m];
        *(half8*)(Wp + (size_t)u * 8) = v;
    } else {
        long i = ((long)(bid - 32) * 256 + threadIdx.x) * 4;
        if (i + 4 <= (long)NF) {
            float4 f = *(const float4*)(x + i);
            half4 v;
            v[0] = (_Float16)f.x; v[1] = (_Float16)f.y;
            v[2] = (_Float16)f.z; v[3] = (_Float16)f.w;
            *(half4*)(xh + i) = v;
        }
    }
}

// ---------------------------------------------------------------------------
// acc init = per-layer bias (exact: acc elem j <-> out-channel ct*16+quad*4+j,
// bias is constant over columns).
// ---------------------------------------------------------------------------
__device__ __forceinline__ void acc_bias_init(
    f32x4 (&acc)[2][8], const float* __restrict__ bias, int quad)
{
    #pragma unroll
    for (int ct = 0; ct < 8; ++ct) {
        float4 bv = *(const float4*)(bias + ct * 16 + quad * 4);
        f32x4 b = {bv.x, bv.y, bv.z, bv.w};
        acc[0][ct] = b;
        acc[1][ct] = b;
    }
}

// ---------------------------------------------------------------------------
// Epilogue: relu(acc) -> fp16 scratch [edge(l15)][hidden] (bias already in
// acc), pull next layer's B-frags back as b128, then re-init acc with the
// NEXT layer's bias.  Scratch row stride 128 halfs (256 B), XOR swizzle
// idx ^= (l15&7)<<3: b64 writes at ~2-way bank aliasing (free), b128 reads
// equivalent to contiguous; 4 KB/wave.
// ---------------------------------------------------------------------------
__device__ __forceinline__ void epi_extract(
    f32x4 (&acc)[2][8], _Float16* __restrict__ scr, int l15, int quad, int sw,
    half8 (&bh)[2][4], const float* __restrict__ next_bias)
{
    #pragma unroll
    for (int nt = 0; nt < 2; ++nt) {
        #pragma unroll
        for (int ct = 0; ct < 8; ++ct) {
            half4 h;
            h[0] = (_Float16)fmaxf(acc[nt][ct][0], 0.f);
            h[1] = (_Float16)fmaxf(acc[nt][ct][1], 0.f);
            h[2] = (_Float16)fmaxf(acc[nt][ct][2], 0.f);
            h[3] = (_Float16)fmaxf(acc[nt][ct][3], 0.f);
            *(half4*)(scr + ((l15 * 128 + ct * 16 + quad * 4) ^ sw)) = h; // ds_write_b64
        }
        #pragma unroll
        for (int ks = 0; ks < 4; ++ks)                                    // ds_read_b128
            bh[nt][ks] = *(const half8*)(scr + ((l15 * 128 + ks * 32 + quad * 8) ^ sw));
    }
    acc_bias_init(acc, next_bias, quad);
}

// ---------------------------------------------------------------------------
// MFMA layer, ct chunked 8 -> 2x4 (R5 spill fix: peak live aw = 16 regs).
// setprio(1) around the MFMA cluster: waves here are independent (no
// barriers in the tile loop) -- the regime where T5 measured +4-7%.
// ---------------------------------------------------------------------------
__device__ __forceinline__ void layer_mfma(
    f32x4 (&acc)[2][8], const _Float16* __restrict__ Wl,
    half8 (&bh)[2][4], int lane)
{
    __builtin_amdgcn_s_setprio(1);
    #pragma unroll
    for (int ks = 0; ks < 4; ++ks) {
        #pragma unroll
        for (int ch = 0; ch < 2; ++ch) {
            half8 aw[4];
            #pragma unroll
            for (int c = 0; c < 4; ++c)
                aw[c] = *(const half8*)(Wl + ((size_t)(((ch * 4 + c) * 4 + ks) * 64 + lane)) * 8);
            #pragma unroll
            for (int nt = 0; nt < 2; ++nt)
                #pragma unroll
                for (int c = 0; c < 4; ++c)
                    acc[nt][ch * 4 + c] = __builtin_amdgcn_mfma_f32_16x16x32_f16(
                        aw[c], bh[nt][ks], acc[nt][ch * 4 + c], 0, 0, 0);
        }
    }
    __builtin_amdgcn_s_setprio(0);
}

// one K-half of layer 1 (ks window [ks0, ks0+4), B-frags bef)
__device__ __forceinline__ void layer1_half(
    f32x4 (&acc)[2][8], const _Float16* __restrict__ W1l,
    half8 (&bef)[2][4], int ks0, int lane)
{
    __builtin_amdgcn_s_setprio(1);
    #pragma unroll
    for (int ks = 0; ks < 4; ++ks) {
        #pragma unroll
        for (int ch = 0; ch < 2; ++ch) {
            half8 aw[4];
            #pragma unroll
            for (int c = 0; c < 4; ++c)
                aw[c] = *(const half8*)(W1l + ((size_t)(((ch * 4 + c) * 8 + ks0 + ks) * 64 + lane)) * 8);
            #pragma unroll
            for (int nt = 0; nt < 2; ++nt)
                #pragma unroll
                for (int c = 0; c < 4; ++c)
                    acc[nt][ch * 4 + c] = __builtin_amdgcn_mfma_f32_16x16x32_f16(
                        aw[c], bef[nt][ks], acc[nt][ch * 4 + c], 0, 0, 0);
        }
    }
    __builtin_amdgcn_s_setprio(0);
}

// ---------------------------------------------------------------------------
// Persistent fused MLP, transposed GEMM: D[hidden][edge] = W^T (A) x ef^T (B).
// grid = 256 blocks x 512 thr (8 waves, 2 waves/SIMD); 160 KiB LDS ->
// 1 block/CU.  Register discipline (R1-R5): arch peak < 128 via nt=2,
// ct-chunked aw, bias-in-acc.  NEW (R6): cross-tile software pipeline --
//   - x_j gather issued at loop top, hidden under L1-half1 MFMAs
//   - next tile's ei loaded after epi1, hidden under L2
//   - next tile's x_i gather issued after epi2, hidden under L3 + tail
// so the ~1.5k-cycle serial gather chain per tile is mostly off the
// critical path.  Peak live sets stay ~110 arch regs (befi_next 32 +
// bh 32 + aw 16 + ptrs), under the 128-arch cliff.
// ---------------------------------------------------------------------------
__global__ __launch_bounds__(512, 2) void edge_mlp_kernel(
    const int* __restrict__ ei, const _Float16* __restrict__ xh,
    const _Float16* __restrict__ wpack,   // W1p|W2p|W3p contiguous, 65536 halfs
    const float* __restrict__ b1, const float* __restrict__ b2,
    const float* __restrict__ b3, const float* __restrict__ W4,
    const float* __restrict__ b4, float* __restrict__ out, int E)
{
    extern __shared__ _Float16 lds[];

    // stage 128 KB of packed weights, once per (persistent) block
    {
        float4* dst = (float4*)lds;
        const float4* src = (const float4*)wpack;
        #pragma unroll
        for (int i = 0; i < 16; ++i)
            dst[i * 512 + threadIdx.x] = src[i * 512 + threadIdx.x];
    }
    __syncthreads();

    const int tid  = threadIdx.x;
    const int wave = tid >> 6;
    const int lane = tid & 63;
    const int l15  = lane & 15;
    const int quad = lane >> 4;
    const int sw   = (l15 & 7) << 3;      // scratch XOR swizzle (halfs)

    const _Float16* W1l = lds;
    const _Float16* W2l = lds + 32768;
    const _Float16* W3l = lds + 49152;
    _Float16* scr = lds + WHALFS + wave * SCR_HALFS;

    const int ntiles = (E + 255) >> 8;    // 256 edges per block tile
    const float b4v = b4[0];

    // ---- pipeline prologue: indices + x_i gather for the first tile ----
    int gi[2], gj[2];
    half8 befi[2][4];
    {
        const int base0 = blockIdx.x * 256 + wave * 32;
        #pragma unroll
        for (int nt = 0; nt < 2; ++nt) {
            const int row = min(base0 + nt * 16 + l15, E - 1);
            gi[nt] = ei[row];
            gj[nt] = ei[E + row];
        }
        #pragma unroll
        for (int nt = 0; nt < 2; ++nt) {
            const _Float16* pi = xh + (size_t)gi[nt] * HDIM;
            #pragma unroll
            for (int ks = 0; ks < 4; ++ks)
                befi[nt][ks] = *(const half8*)(pi + ks * 32 + quad * 8);
        }
    }

    for (int t = blockIdx.x; t < ntiles; t += gridDim.x) {
        const int base = t * 256 + wave * 32;

        // ---- issue x_j gather now; it flies under L1-half1's MFMAs ----
        half8 befj[2][4];
        #pragma unroll
        for (int nt = 0; nt < 2; ++nt) {
            const _Float16* pj = xh + (size_t)gj[nt] * HDIM;
            #pragma unroll
            for (int ks = 0; ks < 4; ++ks)
                befj[nt][ks] = *(const half8*)(pj + ks * 32 + quad * 8);
        }

        f32x4 acc[2][8];
        acc_bias_init(acc, b1, quad);

        // ---- layer 1: K = 0..127 (x_i, prefetched last iteration) ----
        layer1_half(acc, W1l, befi, 0, lane);
        // ---- layer 1: K = 128..255 (x_j, issued above) ----
        layer1_half(acc, W1l, befj, 4, lane);

        half8 bh[2][4];
        epi_extract(acc, scr, l15, quad, sw, bh, b2);  // h1 -> B-frags, acc=b2

        // ---- prefetch next tile's edge indices (hidden under L2) ----
        int gin[2], gjn[2];
        {
            const int basen = (t + (int)gridDim.x) * 256 + wave * 32;
            #pragma unroll
            for (int nt = 0; nt < 2; ++nt) {
                const int row = min(min(basen + nt * 16 + l15, E - 1), E - 1);
                gin[nt] = ei[row];
                gjn[nt] = ei[E + row];
            }
        }

        layer_mfma(acc, W2l, bh, lane);                // layer 2
        epi_extract(acc, scr, l15, quad, sw, bh, b3);  // h2 -> B-frags, acc=b3

        // ---- prefetch next tile's x_i gather (hidden under L3 + tail) ----
        #pragma unroll
        for (int nt = 0; nt < 2; ++nt) {
            const _Float16* pi = xh + (size_t)gin[nt] * HDIM;
            #pragma unroll
            for (int ks = 0; ks < 4; ++ks)
                befi[nt][ks] = *(const half8*)(pi + ks * 32 + quad * 8);
        }

        layer_mfma(acc, W3l, bh, lane);                // layer 3 (acc has b3)

        // ---- layer 4: per-edge dot over hidden + sigmoid ----
        #pragma unroll
        for (int nt = 0; nt < 2; ++nt) {
            float s = 0.f;
            #pragma unroll
            for (int ct = 0; ct < 8; ++ct) {
                float4 w4v = *(const float4*)(W4 + ct * 16 + quad * 4);
                s += fmaxf(acc[nt][ct][0], 0.f) * w4v.x;
                s += fmaxf(acc[nt][ct][1], 0.f) * w4v.y;
                s += fmaxf(acc[nt][ct][2], 0.f) * w4v.z;
                s += fmaxf(acc[nt][ct][3], 0.f) * w4v.w;
            }
            s += __shfl_xor(s, 16, 64);   // sum across quads (same l15)
            s += __shfl_xor(s, 32, 64);
            const int row = base + nt * 16 + l15;
            if (quad == 0 && row < E)
                out[row] = 1.f / (1.f + __expf(-(s + b4v)));
        }

        // rotate pipeline registers
        gi[0] = gin[0]; gi[1] = gin[1];
        gj[0] = gjn[0]; gj[1] = gjn[1];
    }
}

// ---------------------------------------------------------------------------
extern "C" void kernel_launch(void* const* d_in, const int* in_sizes, int n_in,
                              void* d_out, int out_size, void* d_ws, size_t ws_size,
                              hipStream_t stream)
{
    const float* x  = (const float*)d_in[0];
    const int*   ei = (const int*)d_in[1];
    const float* W1 = (const float*)d_in[2];
    const float* b1 = (const float*)d_in[3];
    const float* W2 = (const float*)d_in[4];
    const float* b2 = (const float*)d_in[5];
    const float* W3 = (const float*)d_in[6];
    const float* b3 = (const float*)d_in[7];
    const float* W4 = (const float*)d_in[8];
    const float* b4 = (const float*)d_in[9];
    float* out = (float*)d_out;

    const int NF = in_sizes[0];    // N*F = 12,800,000
    const int E  = out_size;       // 625,000

    // ws layout (halfs): [ xh : NF ][ W1p : 32768 ][ W2p : 16384 ][ W3p : 16384 ]
    _Float16* xh  = (_Float16*)d_ws;
    _Float16* W1p = xh + NF;
    _Float16* W2p = W1p + 32768;
    _Float16* W3p = W2p + 16384;

    const int xblocks = (NF + 1023) / 1024;
    prep_kernel<<<32 + xblocks, 256, 0, stream>>>(x, W1, W2, W3, xh, W1p, W2p, W3p, NF);

    hipFuncSetAttribute((const void*)edge_mlp_kernel,
                        hipFuncAttributeMaxDynamicSharedMemorySize, LDS_BYTES);
    edge_mlp_kernel<<<256, 512, LDS_BYTES, stream>>>(ei, xh, W1p,
                                                     b1, b2, b3, W4, b4, out, E);
}